// Round 5
// baseline (43906.360 us; speedup 1.0000x reference)
//
#include <hip/hip_runtime.h>
#include <stdint.h>

typedef unsigned short u16;
typedef unsigned int   u32;
typedef unsigned long long u64;
typedef __attribute__((ext_vector_type(4)))  int   i32x4;
typedef __attribute__((ext_vector_type(4)))  float f32x4;
typedef __attribute__((ext_vector_type(8)))  u16   u16x8;
typedef __attribute__((ext_vector_type(8)))  short s16x8;

typedef __attribute__((address_space(3))) char  as3_char;
typedef __attribute__((address_space(3))) i32x4 as3_i32x4;
typedef __attribute__((address_space(3))) s16x8 as3_s16x8;

#define B_    64
#define T_    512
#define DIN_  512
#define H_    1024
#define NBLK_ 64
#define NTHR_ 512

#define HN_BASE_  (64ull*512*1024)
#define CN_BASE_  (HN_BASE_ + 2ull*64*1024)

// ---- workspace layout (bytes) ----
#define WB0_OFF  0ull
#define WB0_SZ   (8ull*512*1536*2)        // [j][c][K] bf16, c = gate*128+hcl
#define WB1_OFF  (WB0_OFF + WB0_SZ)
#define WB1_SZ   (8ull*512*2048*2)
#define XT_OFF   (WB1_OFF + WB1_SZ)
#define XT_SZ    (512ull*64*512*2)        // [t][b][d] bf16
#define HB_OFF   (XT_OFF + XT_SZ)
#define HBUF_    131072ull                // one [64][1024] bf16 buffer
// h0[2], h1[2]  (parity-indexed double buffers)
#define BIAS_OFF (HB_OFF + 4*HBUF_)
#define SYNC_OFF (BIAS_OFF + 32768)

__device__ __forceinline__ u16 f2bf(float f) {   // RNE fp32 -> bf16
  u32 u = __builtin_bit_cast(u32, f);
  return (u16)((u + 0x7FFFu + ((u >> 16) & 1u)) >> 16);
}
__device__ __forceinline__ float sigf(float x) {
  float e = __builtin_amdgcn_exp2f(x * -1.442695041f);
  return __builtin_amdgcn_rcpf(1.0f + e);
}
__device__ __forceinline__ float tanhf_fast(float x) {
  float e = __builtin_amdgcn_exp2f(x * -2.885390082f);
  float r = __builtin_amdgcn_rcpf(1.0f + e);
  return fmaf(2.0f, r, -1.0f);
}

#define VMW(n)  asm volatile("s_waitcnt vmcnt(" #n ")" ::: "memory")
#define GLOADC(dst, a)  asm volatile("global_load_dwordx4 %0, %1, off sc0 sc1" : "=v"(dst) : "v"(a))

// ============================ prep kernels ============================

__global__ void prep_misc(const float* __restrict__ bih0, const float* __restrict__ bhh0,
                          const float* __restrict__ bih1, const float* __restrict__ bhh1,
                          float* __restrict__ bias, u32* __restrict__ hz,
                          u32* __restrict__ sync)
{
  int i = blockIdx.x * 256 + threadIdx.x;        // 1024*256 = 262144 threads
  if (i < 4096) bias[i] = bih0[i] + bhh0[i];
  else if (i < 8192) bias[i] = bih1[i - 4096] + bhh1[i - 4096];
  if (i < 131072) hz[i] = 0u;                    // zero h0[2], h1[2] (512 KB)
  if (i < 256) sync[i] = 0u;
}

// W[k][n] fp32 -> Wb[j][c][K] bf16 col-major slices, j=hcol>>7, c=gate*128+(hcol&127)
__global__ void prep_w(const float* __restrict__ Wih0, const float* __restrict__ Whh0,
                       const float* __restrict__ Wih1, const float* __restrict__ Whh1,
                       u16* __restrict__ Wb0, u16* __restrict__ Wb1)
{
  __shared__ u16 tile[64][72];
  const int bid = blockIdx.x;
  const int layer = (bid >= 1536) ? 1 : 0;
  const int lb = layer ? bid - 1536 : bid;
  const int nkt = layer ? 32 : 24;
  const int kt = lb % nkt, nt = lb / nkt;
  const int K = layer ? 2048 : 1536;
  const int xlen = layer ? 1024 : 512;
  const float* Wih = layer ? Wih1 : Wih0;
  const float* Whh = layer ? Whh1 : Whh0;
  u16* Wb = layer ? Wb1 : Wb0;
  const int k0 = kt * 64, n0 = nt * 64;
  const int t = threadIdx.x;
  {
    int kr = t >> 2, ncs = (t & 3) * 16;
    int kk = k0 + kr;
    const float* src = (kk < xlen) ? (Wih + (size_t)kk * 4096)
                                   : (Whh + (size_t)(kk - xlen) * 4096);
    const float* p = src + n0 + ncs;
#pragma unroll
    for (int v = 0; v < 4; ++v) {
      f32x4 f = *(const f32x4*)(p + v * 4);
#pragma unroll
      for (int e = 0; e < 4; ++e) tile[kr][ncs + v*4 + e] = f2bf(f[e]);
    }
  }
  __syncthreads();
  {
    int c = t >> 2;
    int n = n0 + c;
    int gate = n >> 10, hcol = n & 1023;
    int jdx = hcol >> 7, cd = gate * 128 + (hcol & 127);
    u16* dstc = Wb + ((size_t)(jdx * 512 + cd) * K + k0);
#pragma unroll
    for (int kv = 0; kv < 2; ++kv) {
      int k8 = (t & 3) + 4 * kv;
      u16x8 vv;
#pragma unroll
      for (int e = 0; e < 8; ++e) vv[e] = tile[k8*8 + e][c];
      *(u16x8*)(dstc + k8 * 8) = vv;
    }
  }
}

// x [b][t][d] fp32 -> xT [t][b][d] bf16
__global__ void prep_x(const float* __restrict__ x, u16* __restrict__ xT)
{
  int i = blockIdx.x * 256 + threadIdx.x;
  int d16 = (i & 31) << 4;
  int b   = (i >> 5) & 63;
  int tt  = i >> 11;
  const float* s = x + ((size_t)b * T_ + tt) * DIN_ + d16;
  u16* d = xT + ((size_t)tt * B_ + b) * DIN_ + d16;
  f32x4 fa = *(const f32x4*)(s);
  f32x4 fb = *(const f32x4*)(s + 4);
  f32x4 fc = *(const f32x4*)(s + 8);
  f32x4 fd = *(const f32x4*)(s + 12);
  u16x8 o0, o1;
#pragma unroll
  for (int e = 0; e < 4; ++e) {
    o0[e] = f2bf(fa[e]); o0[4+e] = f2bf(fb[e]);
    o1[e] = f2bf(fc[e]); o1[4+e] = f2bf(fd[e]);
  }
  *(u16x8*)d = o0;
  *(u16x8*)(d + 8) = o1;
}

// ============================ persistent LSTM kernel ============================
// 64 blocks x 512 threads. bid = layer*32 + i*8 + j : i = row-group (16 batch rows),
// j = col-group (128 h-cols = 512 gate-cols) = XCD. Block computes gates [16 x 512]
// with FULL K each step. A (x|h) staged to LDS (padded rows, NO swizzle):
// issue loads -> vmcnt(0) -> sched_barrier -> LDS write. GEMM is PURE INTRINSIC
// mfma_f32_16x16x32_bf16 with plain C loads -- compiler schedules all waits and
// hazards (bisection: removes all hand-rolled asm/vmcnt/ring machinery).
// ONE grid barrier over all 64 blocks (proven round-1/2 pattern).

template<int LAYER>
__device__ __forceinline__ void phase(
    const int t, const int i16, const int tid,
    const u16* __restrict__ xt, const char* __restrict__ wb,
    const char* __restrict__ srcH0, const char* __restrict__ srcH1,
    u16* __restrict__ wr,
    const float b0, const float b1, const float b2, const float b3,
    const int colg, const int hcl, const int r4, float (&cst)[4],
    float* __restrict__ out, as3_char* ldsA, float* gatesL)
{
  constexpr int K   = LAYER ? 2048 : 1536;
  constexpr int RS  = K * 2 + 32;        // padded LDS row stride (bytes)
  constexpr int NS  = K / 64;            // k64 slices
  constexpr int CH  = LAYER ? 8 : 6;     // 16B chunks per thread (A staging)
  constexpr int CPR = K / 8;             // 16B chunks per A row
  const int lane = tid & 63, w = tid >> 6;
  const int l15 = lane & 15, lg = lane >> 4;
  const int colb = w * 64;

  // ---- stage A: issue loads (x plain C, h coherent asm), vmcnt(0), LDS write ----
  i32x4 st[8]; int dsd[8];
#pragma unroll
  for (int c = 0; c < CH; ++c) {
    int ch = c * 512 + tid;
    int row = ch / CPR, k16 = ch - row * CPR;
    if (LAYER == 0) {
      if (k16 < 64) {
        st[c] = *(const i32x4*)((const char*)xt + ((size_t)(i16 + row) * 512 + k16 * 8) * 2);
      } else {
        u64 a = (u64)(srcH0 + ((size_t)(i16 + row) * 1024 + (k16 - 64) * 8) * 2);
        GLOADC(st[c], a);
      }
    } else {
      const char* bs = (k16 < 128) ? srcH0 : srcH1;
      int kk = (k16 < 128) ? k16 : k16 - 128;
      u64 a = (u64)(bs + ((size_t)(i16 + row) * 1024 + kk * 8) * 2);
      GLOADC(st[c], a);
    }
    dsd[c] = row * RS + k16 * 16;
  }
  VMW(0);
  __builtin_amdgcn_sched_barrier(0);
#pragma unroll
  for (int c = 0; c < CH; ++c) *(as3_i32x4*)(ldsA + dsd[c]) = st[c];
  __syncthreads();

  // ---- MFMA main loop: pure intrinsics, compiler-scheduled ----
  f32x4 acc[4] = {};
  const as3_char* arow = ldsA + l15 * RS;
  const char* bcol[4];
#pragma unroll
  for (int n = 0; n < 4; ++n)
    bcol[n] = wb + (((size_t)(colb + n * 16 + l15)) * K + lg * 8) * 2;

#pragma unroll
  for (int jj = 0; jj < NS; ++jj) {
    s16x8 a0 = *(const as3_s16x8*)(arow + jj * 128 + lg * 16);
    s16x8 a1 = *(const as3_s16x8*)(arow + jj * 128 + 64 + lg * 16);
#pragma unroll
    for (int n = 0; n < 4; ++n) {
      s16x8 bv0 = *(const s16x8*)(bcol[n] + jj * 128);
      s16x8 bv1 = *(const s16x8*)(bcol[n] + jj * 128 + 64);
      acc[n] = __builtin_amdgcn_mfma_f32_16x16x32_bf16(a0, bv0, acc[n], 0, 0, 0);
      acc[n] = __builtin_amdgcn_mfma_f32_16x16x32_bf16(a1, bv1, acc[n], 0, 0, 0);
    }
  }

  // ---- gates exchange: [col][row] fp32, stride 20 ----
#pragma unroll
  for (int n = 0; n < 4; ++n) {
    int cl = colb + n * 16 + l15;
    *(f32x4*)(gatesL + (size_t)cl * 20 + lg * 4) = acc[n];
  }
  __syncthreads();

  // ---- cell update: thread = (hcl, rows 4*r4..+4) ----
#pragma unroll
  for (int e = 0; e < 4; ++e) {
    int row = 4 * r4 + e;
    float g0 = gatesL[(size_t)(0 * 128 + hcl) * 20 + row];
    float g1 = gatesL[(size_t)(1 * 128 + hcl) * 20 + row];
    float g2 = gatesL[(size_t)(2 * 128 + hcl) * 20 + row];
    float g3 = gatesL[(size_t)(3 * 128 + hcl) * 20 + row];
    float ig = sigf(g0 + b0);
    float fg = sigf(g1 + b1);
    float cg = fmaxf(g2 + b2, 0.0f);
    float og = sigf(g3 + b3);
    float cn = fg * cst[e] + ig * cg;
    cst[e] = cn;
    float h = og * tanhf_fast(cn);
    u32 hb = (u32)f2bf(h);
    int rowg = i16 + row;
    u64 a0 = (u64)((char*)wr + ((size_t)rowg * 1024 + colg) * 2);
    asm volatile("global_store_short %0, %1, off sc0 sc1" :: "v"(a0), "v"(hb) : "memory");
    if (LAYER == 1) out[((size_t)rowg * T_ + t) * H_ + colg] = h;
    if (t == T_ - 1) {
      out[HN_BASE_ + ((size_t)LAYER * 64 + rowg) * H_ + colg] = h;
      out[CN_BASE_ + ((size_t)LAYER * 64 + rowg) * H_ + colg] = cn;
    }
  }
}

__global__ __launch_bounds__(NTHR_, 1) void lstm_persist(
    const u16* __restrict__ xT, const u16* __restrict__ Wb0, const u16* __restrict__ Wb1,
    char* __restrict__ hb, const float* __restrict__ bias,
    u32* __restrict__ sync, float* __restrict__ out)
{
  __shared__ __align__(16) char ldsAraw[16 * (2048 * 2 + 32)];   // 66048 B (max layer)
  __shared__ __align__(16) float gatesL[512 * 20];
  as3_char* ldsA = (as3_char*)ldsAraw;
  const int tid = threadIdx.x;
  const int bid = blockIdx.x;
  const int layer = bid >> 5, i = (bid >> 3) & 3, j = bid & 7;
  const int i16 = i * 16;
  const char* wb = layer ? ((const char*)Wb1 + (size_t)j * 512 * 2048 * 2)
                         : ((const char*)Wb0 + (size_t)j * 512 * 1536 * 2);
  char* h0 = hb;                        // [par][64][1024] bf16
  char* h1 = hb + 2 * HBUF_;
  const int hcl = tid & 127, r4 = tid >> 7;
  const int colg = j * 128 + hcl;
  float b0, b1, b2, b3;
  {
    const float* bb = bias + layer * 4096;
    b0 = bb[colg]; b1 = bb[1024 + colg]; b2 = bb[2048 + colg]; b3 = bb[3072 + colg];
  }
  float cst[4] = {0.f, 0.f, 0.f, 0.f};

  for (int s = 0; s <= T_; ++s) {
    const size_t rp = (size_t)((s + 1) & 1) * HBUF_;
    const size_t wp = (size_t)(s & 1) * HBUF_;
    if (layer == 0) {
      if (s < T_)
        phase<0>(s, i16, tid, xT + (size_t)s * B_ * DIN_, wb,
                 h0 + rp, nullptr, (u16*)(h0 + wp),
                 b0, b1, b2, b3, colg, hcl, r4, cst, out, ldsA, gatesL);
    } else {
      if (s >= 1)
        phase<1>(s - 1, i16, tid, nullptr, wb,
                 h0 + rp, h1 + rp, (u16*)(h1 + wp),
                 b0, b1, b2, b3, colg, hcl, r4, cst, out, ldsA, gatesL);
    }
    // ---- single grid barrier over all 64 blocks ----
    VMW(0);
    __syncthreads();
    if (tid == 0) {
      __hip_atomic_fetch_add(sync, 1u, __ATOMIC_RELAXED, __HIP_MEMORY_SCOPE_AGENT);
      u32 tgt = (u32)(s + 1) * (u32)NBLK_;
      while (__hip_atomic_load(sync, __ATOMIC_RELAXED, __HIP_MEMORY_SCOPE_AGENT) < tgt)
        __builtin_amdgcn_s_sleep(1);
    }
    __syncthreads();
  }
}

// ============================ host launch ============================

extern "C" void kernel_launch(void* const* d_in, const int* in_sizes, int n_in,
                              void* d_out, int out_size, void* d_ws, size_t ws_size,
                              hipStream_t stream)
{
  const float* x    = (const float*)d_in[0];
  const float* Wih0 = (const float*)d_in[1];
  const float* bih0 = (const float*)d_in[2];
  const float* Whh0 = (const float*)d_in[3];
  const float* bhh0 = (const float*)d_in[4];
  const float* Wih1 = (const float*)d_in[5];
  const float* bih1 = (const float*)d_in[6];
  const float* Whh1 = (const float*)d_in[7];
  const float* bhh1 = (const float*)d_in[8];

  char* ws = (char*)d_ws;
  u16* Wb0    = (u16*)(ws + WB0_OFF);
  u16* Wb1    = (u16*)(ws + WB1_OFF);
  u16* xT     = (u16*)(ws + XT_OFF);
  char* hb    = ws + HB_OFF;
  float* bias = (float*)(ws + BIAS_OFF);
  u32* sync   = (u32*)(ws + SYNC_OFF);
  float* out  = (float*)d_out;

  prep_misc<<<1024, 256, 0, stream>>>(bih0, bhh0, bih1, bhh1, bias, (u32*)hb, sync);
  prep_w<<<3584, 256, 0, stream>>>(Wih0, Whh0, Wih1, Whh1, Wb0, Wb1);
  prep_x<<<4096, 256, 0, stream>>>(x, xT);
  lstm_persist<<<NBLK_, NTHR_, 0, stream>>>(xT, Wb0, Wb1, hb, bias, sync, out);
}

// Round 6
// 9700.868 us; speedup vs baseline: 4.5260x; 4.5260x over previous
//
#include <hip/hip_runtime.h>
#include <stdint.h>

typedef unsigned short u16;
typedef unsigned int   u32;
typedef unsigned long long u64;
typedef __attribute__((ext_vector_type(4)))  int   i32x4;
typedef __attribute__((ext_vector_type(4)))  float f32x4;
typedef __attribute__((ext_vector_type(8)))  u16   u16x8;
typedef __attribute__((ext_vector_type(8)))  short s16x8;

typedef __attribute__((address_space(3))) char  as3_char;
typedef __attribute__((address_space(3))) i32x4 as3_i32x4;
typedef __attribute__((address_space(3))) s16x8 as3_s16x8;

#define B_    64
#define T_    512
#define DIN_  512
#define H_    1024
#define NBLK_ 256
#define NTHR_ 512

#define HN_BASE_  (64ull*512*1024)
#define CN_BASE_  (HN_BASE_ + 2ull*64*1024)

// ---- workspace layout (bytes) ----
#define WB0_OFF  0ull
#define WB0_SZ   (64ull*64*1536*2)        // [grp][cd][K] bf16, grp=hcol>>4, cd=gate*16+(hcol&15)
#define WB1_OFF  (WB0_OFF + WB0_SZ)
#define WB1_SZ   (64ull*64*2048*2)
#define XT_OFF   (WB1_OFF + WB1_SZ)
#define XT_SZ    (512ull*64*512*2)        // [t][b][d] bf16
#define HB_OFF   (XT_OFF + XT_SZ)
#define HBUF_    131072ull                // one [64][1024] bf16 buffer
// h0[2], h1[2]  (parity-indexed double buffers)
#define BIAS_OFF (HB_OFF + 4*HBUF_)
#define SYNC_OFF (BIAS_OFF + 32768)

__device__ __forceinline__ u16 f2bf(float f) {   // RNE fp32 -> bf16
  u32 u = __builtin_bit_cast(u32, f);
  return (u16)((u + 0x7FFFu + ((u >> 16) & 1u)) >> 16);
}
__device__ __forceinline__ float sigf(float x) {
  float e = __builtin_amdgcn_exp2f(x * -1.442695041f);
  return __builtin_amdgcn_rcpf(1.0f + e);
}
__device__ __forceinline__ float tanhf_fast(float x) {
  float e = __builtin_amdgcn_exp2f(x * -2.885390082f);
  float r = __builtin_amdgcn_rcpf(1.0f + e);
  return fmaf(2.0f, r, -1.0f);
}

#define VMW(n)  asm volatile("s_waitcnt vmcnt(" #n ")" ::: "memory")
#define GLOADC(dst, a)  asm volatile("global_load_dwordx4 %0, %1, off sc0 sc1" : "=v"(dst) : "v"(a))

// ============================ prep kernels ============================

__global__ void prep_misc(const float* __restrict__ bih0, const float* __restrict__ bhh0,
                          const float* __restrict__ bih1, const float* __restrict__ bhh1,
                          float* __restrict__ bias, u32* __restrict__ hz,
                          u32* __restrict__ sync)
{
  int i = blockIdx.x * 256 + threadIdx.x;        // 1024*256 = 262144 threads
  if (i < 4096) bias[i] = bih0[i] + bhh0[i];
  else if (i < 8192) bias[i] = bih1[i - 4096] + bhh1[i - 4096];
  if (i < 131072) hz[i] = 0u;                    // zero h0[2], h1[2] (512 KB)
  if (i < 256) sync[i] = 0u;
}

// W[k][n] fp32 -> Wb[grp][cd][K] bf16, grp=hcol>>4 (64 groups of 16 h-cols),
// cd = gate*16 + (hcol&15).  (round-1/2 proven version)
__global__ void prep_w(const float* __restrict__ Wih0, const float* __restrict__ Whh0,
                       const float* __restrict__ Wih1, const float* __restrict__ Whh1,
                       u16* __restrict__ Wb0, u16* __restrict__ Wb1)
{
  __shared__ u16 tile[64][72];
  const int bid = blockIdx.x;
  const int layer = (bid >= 1536) ? 1 : 0;
  const int lb = layer ? bid - 1536 : bid;
  const int nkt = layer ? 32 : 24;
  const int kt = lb % nkt, nt = lb / nkt;
  const int K = layer ? 2048 : 1536;
  const int xlen = layer ? 1024 : 512;
  const float* Wih = layer ? Wih1 : Wih0;
  const float* Whh = layer ? Whh1 : Whh0;
  u16* Wb = layer ? Wb1 : Wb0;
  const int k0 = kt * 64, n0 = nt * 64;
  const int t = threadIdx.x;
  {
    int kr = t >> 2, ncs = (t & 3) * 16;
    int kk = k0 + kr;
    const float* src = (kk < xlen) ? (Wih + (size_t)kk * 4096)
                                   : (Whh + (size_t)(kk - xlen) * 4096);
    const float* p = src + n0 + ncs;
#pragma unroll
    for (int v = 0; v < 4; ++v) {
      f32x4 f = *(const f32x4*)(p + v * 4);
#pragma unroll
      for (int e = 0; e < 4; ++e) tile[kr][ncs + v*4 + e] = f2bf(f[e]);
    }
  }
  __syncthreads();
  {
    int c = t >> 2;
    int n = n0 + c;
    int gate = n >> 10, hcol = n & 1023;
    int grp = hcol >> 4, cd = gate * 16 + (hcol & 15);
    u16* dstc = Wb + ((size_t)(grp * 64 + cd) * K + k0);
#pragma unroll
    for (int kv = 0; kv < 2; ++kv) {
      int k8 = (t & 3) + 4 * kv;
      u16x8 vv;
#pragma unroll
      for (int e = 0; e < 8; ++e) vv[e] = tile[k8*8 + e][c];
      *(u16x8*)(dstc + k8 * 8) = vv;
    }
  }
}

// x [b][t][d] fp32 -> xT [t][b][d] bf16
__global__ void prep_x(const float* __restrict__ x, u16* __restrict__ xT)
{
  int i = blockIdx.x * 256 + threadIdx.x;
  int d16 = (i & 31) << 4;
  int b   = (i >> 5) & 63;
  int tt  = i >> 11;
  const float* s = x + ((size_t)b * T_ + tt) * DIN_ + d16;
  u16* d = xT + ((size_t)tt * B_ + b) * DIN_ + d16;
  f32x4 fa = *(const f32x4*)(s);
  f32x4 fb = *(const f32x4*)(s + 4);
  f32x4 fc = *(const f32x4*)(s + 8);
  f32x4 fd = *(const f32x4*)(s + 12);
  u16x8 o0, o1;
#pragma unroll
  for (int e = 0; e < 4; ++e) {
    o0[e] = f2bf(fa[e]); o0[4+e] = f2bf(fb[e]);
    o1[e] = f2bf(fc[e]); o1[4+e] = f2bf(fd[e]);
  }
  *(u16x8*)d = o0;
  *(u16x8*)(d + 8) = o1;
}

// ============================ persistent LSTM kernel ============================
// 256 blocks x 512 threads (1/CU, all CUs). bid = layer*128 + i*64 + j:
//   layer in {0,1}; i in {0,1} = 32-row half; j in {0..63} = 16 h-cols (64 gate-cols).
//   XCD = bid%8 = j%8 -> per-XCD weight footprint 3.67 MB (round-2-proven resident).
// Block computes gates [32 x 64] with FULL K. A (x|h) staged to LDS via one deep
// burst (12-16 outstanding dwordx4/thread), issue-all -> vmcnt(0) -> LDS (round-5
// proven). GEMM: wave w = (m=w>>2, n=w&3) owns ONE 16x16 C tile, full K, pure
// intrinsic mfma_16x16x32_bf16, 2 interleaved accumulators; B plain loads from L2.
// Tree grid barrier: 8 leaves x 32 + root (round-2 proven).

template<int LAYER>
__device__ __forceinline__ void phase(
    const int t, const int i32b, const int tid,
    const u16* __restrict__ xt, const char* __restrict__ wb,
    const char* __restrict__ srcH0, const char* __restrict__ srcH1,
    u16* __restrict__ wr,
    const float b0, const float b1, const float b2, const float b3,
    const int colg, float& cst,
    float* __restrict__ out, as3_char* ldsA, float* gatesL)
{
  constexpr int K   = LAYER ? 2048 : 1536;
  constexpr int RS  = K * 2 + 32;        // padded LDS row stride (bytes)
  constexpr int NS  = K / 32;            // k32 slices
  constexpr int CH  = LAYER ? 16 : 12;   // 16B chunks per thread (A staging)
  constexpr int CPR = K / 8;             // 16B chunks per A row
  const int lane = tid & 63, w = tid >> 6;
  const int l15 = lane & 15, lg = lane >> 4;
  const int wm = w >> 2, wn = w & 3;

  // ---- stage A [32 rows x K]: issue ALL loads (deep burst), vmcnt(0), LDS ----
  i32x4 st[16]; int dsd[16];
#pragma unroll
  for (int c = 0; c < CH; ++c) {
    int ch = c * 512 + tid;
    int row = ch / CPR, k16 = ch - row * CPR;
    if (LAYER == 0) {
      if (k16 < 64) {
        st[c] = *(const i32x4*)((const char*)xt + ((size_t)(i32b + row) * 512 + k16 * 8) * 2);
      } else {
        u64 a = (u64)(srcH0 + ((size_t)(i32b + row) * 1024 + (k16 - 64) * 8) * 2);
        GLOADC(st[c], a);
      }
    } else {
      const char* bs = (k16 < 128) ? srcH0 : srcH1;
      int kk = (k16 < 128) ? k16 : k16 - 128;
      u64 a = (u64)(bs + ((size_t)(i32b + row) * 1024 + kk * 8) * 2);
      GLOADC(st[c], a);
    }
    dsd[c] = row * RS + k16 * 16;
  }
  VMW(0);
  __builtin_amdgcn_sched_barrier(0);
#pragma unroll
  for (int c = 0; c < CH; ++c) *(as3_i32x4*)(ldsA + dsd[c]) = st[c];
  __syncthreads();

  // ---- GEMM: one 16x16 tile per wave, full K, 2 interleaved accumulators ----
  f32x4 ac0 = {}, ac1 = {};
  const as3_char* arow = ldsA + (size_t)(wm * 16 + l15) * RS;
  const char* bbase = wb + (((size_t)(wn * 16 + l15)) * K + lg * 8) * 2;
#pragma unroll
  for (int jj = 0; jj < NS; jj += 2) {
    s16x8 a0 = *(const as3_s16x8*)(arow + jj * 64 + lg * 16);
    s16x8 a1 = *(const as3_s16x8*)(arow + (jj + 1) * 64 + lg * 16);
    s16x8 bv0 = *(const s16x8*)(bbase + jj * 64);
    s16x8 bv1 = *(const s16x8*)(bbase + (jj + 1) * 64);
    ac0 = __builtin_amdgcn_mfma_f32_16x16x32_bf16(a0, bv0, ac0, 0, 0, 0);
    ac1 = __builtin_amdgcn_mfma_f32_16x16x32_bf16(a1, bv1, ac1, 0, 0, 0);
  }
  f32x4 acc = ac0 + ac1;

  // ---- gates exchange: gatesL[cd(64)][row(36 pad)] fp32 ----
  *(f32x4*)(gatesL + (size_t)(wn * 16 + l15) * 36 + wm * 16 + lg * 4) = acc;
  __syncthreads();

  // ---- cell update: thread = (hc=tid&15, row=tid>>4), 1 c-elem/thread ----
  {
    const int hc = tid & 15, row = tid >> 4;
    float g0 = gatesL[(size_t)(0 * 16 + hc) * 36 + row];
    float g1 = gatesL[(size_t)(1 * 16 + hc) * 36 + row];
    float g2 = gatesL[(size_t)(2 * 16 + hc) * 36 + row];
    float g3 = gatesL[(size_t)(3 * 16 + hc) * 36 + row];
    float ig = sigf(g0 + b0);
    float fg = sigf(g1 + b1);
    float cg = fmaxf(g2 + b2, 0.0f);
    float og = sigf(g3 + b3);
    float cn = fg * cst + ig * cg;
    cst = cn;
    float h = og * tanhf_fast(cn);
    u32 hb = (u32)f2bf(h);
    int rowg = i32b + row;
    u64 a0 = (u64)((char*)wr + ((size_t)rowg * 1024 + colg) * 2);
    asm volatile("global_store_short %0, %1, off sc0 sc1" :: "v"(a0), "v"(hb) : "memory");
    if (LAYER == 1) out[((size_t)rowg * T_ + t) * H_ + colg] = h;
    if (t == T_ - 1) {
      out[HN_BASE_ + ((size_t)LAYER * 64 + rowg) * H_ + colg] = h;
      out[CN_BASE_ + ((size_t)LAYER * 64 + rowg) * H_ + colg] = cn;
    }
  }
}

__global__ __launch_bounds__(NTHR_, 2) void lstm_persist(
    const u16* __restrict__ xT, const u16* __restrict__ Wb0, const u16* __restrict__ Wb1,
    char* __restrict__ hb, const float* __restrict__ bias,
    u32* __restrict__ sync, float* __restrict__ out)
{
  __shared__ __align__(16) char ldsAraw[32 * (2048 * 2 + 32)];   // 132 KB (max layer)
  __shared__ __align__(16) float gatesL[64 * 36];
  as3_char* ldsA = (as3_char*)ldsAraw;
  const int tid = threadIdx.x;
  const int bid = blockIdx.x;
  const int layer = bid >> 7, i = (bid >> 6) & 1, j = bid & 63;
  const int i32b = i * 32;
  const char* wb = layer ? ((const char*)Wb1 + (size_t)j * 64 * 2048 * 2)
                         : ((const char*)Wb0 + (size_t)j * 64 * 1536 * 2);
  char* h0 = hb;                        // [par][64][1024] bf16
  char* h1 = hb + 2 * HBUF_;
  const int colg = j * 16 + (tid & 15);
  float b0, b1, b2, b3;
  {
    const float* bb = bias + layer * 4096;
    b0 = bb[colg]; b1 = bb[1024 + colg]; b2 = bb[2048 + colg]; b3 = bb[3072 + colg];
  }
  float cst = 0.f;

  for (int s = 0; s <= T_; ++s) {
    const size_t rp = (size_t)((s + 1) & 1) * HBUF_;
    const size_t wp = (size_t)(s & 1) * HBUF_;
    if (layer == 0) {
      if (s < T_)
        phase<0>(s, i32b, tid, xT + (size_t)s * B_ * DIN_, wb,
                 h0 + rp, nullptr, (u16*)(h0 + wp),
                 b0, b1, b2, b3, colg, cst, out, ldsA, gatesL);
    } else {
      if (s >= 1)
        phase<1>(s - 1, i32b, tid, nullptr, wb,
                 h0 + rp, h1 + rp, (u16*)(h1 + wp),
                 b0, b1, b2, b3, colg, cst, out, ldsA, gatesL);
    }
    // ---- tree grid barrier: 8 leaves x 32 -> root -> broadcast flag ----
    VMW(0);
    __syncthreads();
    if (tid == 0) {
      u32* leaf = sync + (bid >> 5) * 16;
      u32 old = __hip_atomic_fetch_add(leaf, 1u, __ATOMIC_RELAXED, __HIP_MEMORY_SCOPE_AGENT);
      if (old == (u32)s * 32u + 31u) {
        u32 r = __hip_atomic_fetch_add(sync + 128, 1u, __ATOMIC_RELAXED, __HIP_MEMORY_SCOPE_AGENT);
        if (r == (u32)s * 8u + 7u)
          __hip_atomic_store(sync + 144, (u32)(s + 1), __ATOMIC_RELAXED, __HIP_MEMORY_SCOPE_AGENT);
      }
      while (__hip_atomic_load(sync + 144, __ATOMIC_RELAXED, __HIP_MEMORY_SCOPE_AGENT) < (u32)(s + 1))
        __builtin_amdgcn_s_sleep(2);
    }
    __syncthreads();
  }
}

// ============================ host launch ============================

extern "C" void kernel_launch(void* const* d_in, const int* in_sizes, int n_in,
                              void* d_out, int out_size, void* d_ws, size_t ws_size,
                              hipStream_t stream)
{
  const float* x    = (const float*)d_in[0];
  const float* Wih0 = (const float*)d_in[1];
  const float* bih0 = (const float*)d_in[2];
  const float* Whh0 = (const float*)d_in[3];
  const float* bhh0 = (const float*)d_in[4];
  const float* Wih1 = (const float*)d_in[5];
  const float* bih1 = (const float*)d_in[6];
  const float* Whh1 = (const float*)d_in[7];
  const float* bhh1 = (const float*)d_in[8];

  char* ws = (char*)d_ws;
  u16* Wb0    = (u16*)(ws + WB0_OFF);
  u16* Wb1    = (u16*)(ws + WB1_OFF);
  u16* xT     = (u16*)(ws + XT_OFF);
  char* hb    = ws + HB_OFF;
  float* bias = (float*)(ws + BIAS_OFF);
  u32* sync   = (u32*)(ws + SYNC_OFF);
  float* out  = (float*)d_out;

  prep_misc<<<1024, 256, 0, stream>>>(bih0, bhh0, bih1, bhh1, bias, (u32*)hb, sync);
  prep_w<<<3584, 256, 0, stream>>>(Wih0, Whh0, Wih1, Whh1, Wb0, Wb1);
  prep_x<<<4096, 256, 0, stream>>>(x, xT);
  lstm_persist<<<NBLK_, NTHR_, 0, stream>>>(xT, Wb0, Wb1, hb, bias, sync, out);
}